// Round 10
// baseline (97.643 us; speedup 1.0000x reference)
//
#include <hip/hip_runtime.h>
#include <math.h>

#define EPS 1e-8f

constexpr int B_ = 128;     // batch
constexpr int Q_ = 20;      // queries per sample
constexpr int D_ = 11;      // feature dim
constexpr int N_ = 100000;  // songs
constexpr int DP_ = 12;     // padded feature dim (3x float4)
constexpr int NPAIR = B_ * Q_;  // 2560
constexpr int NCH = 1000;   // song chunks
constexpr int CS = N_ / NCH;   // 100 songs per chunk
constexpr int NG = CS / 4;     // 25 4-song groups per chunk
constexpr int TPB10 = 256;  // sim block size (4 waves)
constexpr int PPT10 = 10;   // pairs per thread: 256*10 = all 2560 pairs per block
constexpr int CPB = 2;      // chunks per block (write-late double buffer)
constexpr int NBLK = NCH / CPB;  // 500 blocks

// ---------------- fused prep: MLP encoder + song pre-normalization ---------------
__global__ void prep_kernel(const float* __restrict__ x,
                            const float* __restrict__ W1, const float* __restrict__ b1,
                            const float* __restrict__ W2, const float* __restrict__ b2,
                            const float* __restrict__ W3, const float* __restrict__ b3,
                            const float* __restrict__ songs,
                            float* __restrict__ pnorm, float* __restrict__ snorm,
                            int do_snorm)
{
    const int t = threadIdx.x;
    if (blockIdx.x >= B_) {
        if (!do_snorm) return;
        const int i = (blockIdx.x - B_) * blockDim.x + t;
        if (i >= N_) return;
        float v[DP_]; float ss = 0.0f;
#pragma unroll
        for (int d = 0; d < D_; ++d) { v[d] = songs[(size_t)i * D_ + d]; ss += v[d] * v[d]; }
        float nrm = fmaxf(sqrtf(ss), EPS);
#pragma unroll
        for (int d = 0; d < D_; ++d) v[d] /= nrm;
        v[D_] = 0.0f;
        float4* o = reinterpret_cast<float4*>(snorm + (size_t)i * DP_);
        o[0] = make_float4(v[0], v[1], v[2], v[3]);
        o[1] = make_float4(v[4], v[5], v[6], v[7]);
        o[2] = make_float4(v[8], v[9], v[10], v[11]);
        return;
    }
    __shared__ float xr[55];
    __shared__ float h1[128];
    __shared__ float h2[64];
    __shared__ float prod[220];
    const int b = blockIdx.x;
    if (t < 55) xr[t] = x[b * 55 + t];
    __syncthreads();
    if (t < 128) {
        float s = b1[t];
        for (int k = 0; k < 55; ++k) s += xr[k] * W1[k * 128 + t];
        h1[t] = fmaxf(s, 0.0f);
    }
    __syncthreads();
    if (t < 64) {
        float s = b2[t];
        for (int k = 0; k < 128; ++k) s += h1[k] * W2[k * 64 + t];
        h2[t] = fmaxf(s, 0.0f);
    }
    __syncthreads();
    if (t < 220) {
        float s = b3[t];
        for (int k = 0; k < 64; ++k) s += h2[k] * W3[k * 220 + t];
        prod[t] = s;
    }
    __syncthreads();
    if (t < Q_) {
        float ss = 0.0f;
        for (int d = 0; d < D_; ++d) { float v = prod[t * D_ + d]; ss += v * v; }
        float nrm = fmaxf(sqrtf(ss), EPS);
        float* o = pnorm + (b * Q_ + t) * DP_;
        for (int d = 0; d < D_; ++d) o[d] = prod[t * D_ + d] / nrm;
        o[D_] = 0.0f;
    }
}

// dot over 11 dims, fixed fmaf sequence (deterministic, identical at every call site)
__device__ __forceinline__ float dot11(const float* __restrict__ q,
                                       const float4 a, const float4 b, const float4 c)
{
    float x = q[0] * a.x;
    x = fmaf(q[1], a.y, x);
    x = fmaf(q[2], a.z, x);
    x = fmaf(q[3], a.w, x);
    x = fmaf(q[4], b.x, x);
    x = fmaf(q[5], b.y, x);
    x = fmaf(q[6], b.z, x);
    x = fmaf(q[7], b.w, x);
    x = fmaf(q[8], c.x, x);
    x = fmaf(q[9], c.y, x);
    x = fmaf(q[10], c.z, x);
    return x;
}

// monotone float -> uint32 (strictly order-preserving for non-NaN)
__device__ __forceinline__ unsigned int fkey(float f)
{
    unsigned int b = __float_as_uint(f);
    return (b & 0x80000000u) ? ~b : (b | 0x80000000u);
}

// pack (value, index): high = monotone value, low = ~idx so that for equal values
// atomicMax keeps the SMALLER index (numpy first-index argmax semantics)
__device__ __forceinline__ unsigned long long pack_vi(float v, int idx)
{
    return ((unsigned long long)fkey(v) << 32) | (unsigned long long)(0xFFFFFFFFu - (unsigned int)idx);
}

// one chunk's 25 groups from an LDS buffer; gi encodes goff+g (ascending order)
__device__ __forceinline__ void chunk_pass(const float4* __restrict__ l4,
                                           const float qv[PPT10][D_],
                                           float* __restrict__ bv, int* __restrict__ gi,
                                           int goff)
{
    const float4* vg = l4;
    for (int g = 0; g < NG; ++g, vg += 12) {
        // songs 0,1 (6 live float4s)
        float4 v0 = vg[0], v1 = vg[1], v2 = vg[2], v3 = vg[3], v4 = vg[4], v5 = vg[5];
        float a0[PPT10], a1[PPT10];
#pragma unroll
        for (int p = 0; p < PPT10; ++p) {
            a0[p] = dot11(qv[p], v0, v1, v2);
            a1[p] = dot11(qv[p], v3, v4, v5);
        }
        // songs 2,3
        float4 w0 = vg[6], w1 = vg[7], w2 = vg[8], w3 = vg[9], w4 = vg[10], w5 = vg[11];
#pragma unroll
        for (int p = 0; p < PPT10; ++p) {
            float a2 = dot11(qv[p], w0, w1, w2);
            float a3 = dot11(qv[p], w3, w4, w5);
            float mx = fmaxf(fmaxf(a0[p], a1[p]), fmaxf(a2, a3));  // v_max3 + v_max
            // strictly-greater keeps FIRST group: numpy first-index argmax semantics
            if (mx > bv[p]) { bv[p] = mx; gi[p] = goff + g; }
        }
    }
}

// ---------------- sim + global argmax: 10 pairs/thread, ALL pairs per block -------
// Grid = 500 blocks x 2 chunks. Every in-loop memory op is a broadcast LDS read;
// query vectors are forced resident (launch_bounds(,1) -> no occupancy pressure).
// Chunk c1 staged write-late: global loads issued at block start, LDS write after
// c0's compute (latency hidden under ~10us of FMAs).
__global__ __launch_bounds__(TPB10, 1)
void sim10_kernel(const float* __restrict__ pnorm,
                  const float* __restrict__ snorm,
                  unsigned long long* __restrict__ res)
{
    __shared__ __align__(16) float lds[CPB][CS * DP_];   // 2 x 4800 B
    const int bid = blockIdx.x;
    const int t = threadIdx.x;
    const int c0 = bid * CPB;

    const float4* s40 = reinterpret_cast<const float4*>(snorm) + (size_t)c0 * CS * 3;
    const float4* s41 = s40 + CS * 3;
    float4* b0 = reinterpret_cast<float4*>(lds[0]);
    float4* b1 = reinterpret_cast<float4*>(lds[1]);

    // stage chunk c0 (300 float4s, 256 threads -> 2 rounds)
    b0[t] = s40[t];
    if (t < CS * 3 - TPB10) b0[t + TPB10] = s40[t + TPB10];
    // issue chunk c1 loads now; LDS-write deferred to after c0 compute
    float4 r0 = s41[t];
    float4 r1 = make_float4(0.f, 0.f, 0.f, 0.f);
    if (t < CS * 3 - TPB10) r1 = s41[t + TPB10];

    // load 10 query vectors (pairs j = t + 256*p) -- target: resident in VGPRs
    float qv[PPT10][D_];
#pragma unroll
    for (int p = 0; p < PPT10; ++p) {
        const float4* q4 = reinterpret_cast<const float4*>(pnorm + (size_t)(t + p * TPB10) * DP_);
        float4 qa = q4[0], qb = q4[1], qc = q4[2];
        qv[p][0] = qa.x; qv[p][1] = qa.y; qv[p][2]  = qa.z; qv[p][3] = qa.w;
        qv[p][4] = qb.x; qv[p][5] = qb.y; qv[p][6]  = qb.z; qv[p][7] = qb.w;
        qv[p][8] = qc.x; qv[p][9] = qc.y; qv[p][10] = qc.z;
    }
    __syncthreads();

    float bv[PPT10]; int gi[PPT10];
#pragma unroll
    for (int p = 0; p < PPT10; ++p) { bv[p] = -1e30f; gi[p] = 0; }

    chunk_pass(b0, qv, bv, gi, 0);

    // write-late: c1 data arrived long ago; store + barrier, then compute
    b1[t] = r0;
    if (t < CS * 3 - TPB10) b1[t + TPB10] = r1;
    __syncthreads();

    chunk_pass(b1, qv, bv, gi, NG);

    // Recompute winning group with the identical fmaf sequence -> bit-exact;
    // descending cascade picks the FIRST in-group index achieving the max.
#pragma unroll
    for (int p = 0; p < PPT10; ++p) {
        const int gsel = gi[p];
        const int cs = (gsel >= NG) ? 1 : 0;
        const int gg = gsel - cs * NG;
        const float4* wg = reinterpret_cast<const float4*>(lds[cs]) + gg * 12;
        float a0 = dot11(qv[p], wg[0], wg[1],  wg[2]);
        float a1 = dot11(qv[p], wg[3], wg[4],  wg[5]);
        float a2 = dot11(qv[p], wg[6], wg[7],  wg[8]);
        float a3 = dot11(qv[p], wg[9], wg[10], wg[11]);
        const int base = (c0 + cs) * CS + gg * 4;
        int idx = base;
        if (a3 == bv[p]) idx = base + 3;
        if (a2 == bv[p]) idx = base + 2;
        if (a1 == bv[p]) idx = base + 1;
        if (a0 == bv[p]) idx = base;
        atomicMax(&res[t + p * TPB10], pack_vi(bv[p], idx));
    }
}

// ---------------- fallback (no snorm workspace): global loads, on-the-fly norm ----
template<int FNCH>
__global__ void sim6f_kernel(const float* __restrict__ pnorm,
                             const float* __restrict__ songs,
                             unsigned long long* __restrict__ res)
{
    constexpr int FCS = N_ / FNCH;
    const int chunk = blockIdx.x;
    const int j = blockIdx.y * 256 + threadIdx.x;

    float qv[D_];
#pragma unroll
    for (int d = 0; d < D_; ++d) qv[d] = pnorm[j * DP_ + d];

    float bestv = -1e30f;
    int   besti = 0;
    const int base = chunk * FCS;
    for (int i = base; i < base + FCS; ++i) {
        float sv[D_]; float ss = 0.0f;
#pragma unroll
        for (int d = 0; d < D_; ++d) { sv[d] = songs[(size_t)i * D_ + d]; ss += sv[d] * sv[d]; }
        float nrm = fmaxf(sqrtf(ss), EPS);
        float a = qv[0] * (sv[0] / nrm);
#pragma unroll
        for (int d = 1; d < D_; ++d) a = fmaf(qv[d], sv[d] / nrm, a);
        if (a > bestv) { bestv = a; besti = i; }
    }
    atomicMax(&res[j], pack_vi(bestv, besti));
}

// ---------------- decode + gather ------------------------------------------------
__global__ void gather_kernel(const unsigned long long* __restrict__ res,
                              const float* __restrict__ songs, float* __restrict__ out)
{
    const int j = blockIdx.x * blockDim.x + threadIdx.x;
    if (j >= NPAIR) return;
    const unsigned int idx = 0xFFFFFFFFu - (unsigned int)(res[j] & 0xFFFFFFFFull);
#pragma unroll
    for (int d = 0; d < D_; ++d) out[(size_t)j * D_ + d] = songs[(size_t)idx * D_ + d];
}

extern "C" void kernel_launch(void* const* d_in, const int* in_sizes, int n_in,
                              void* d_out, int out_size, void* d_ws, size_t ws_size,
                              hipStream_t stream)
{
    const float* x     = (const float*)d_in[0];
    const float* W1    = (const float*)d_in[1];
    const float* b1    = (const float*)d_in[2];
    const float* W2    = (const float*)d_in[3];
    const float* b2    = (const float*)d_in[4];
    const float* W3    = (const float*)d_in[5];
    const float* b3    = (const float*)d_in[6];
    const float* songs = (const float*)d_in[7];
    float* out = (float*)d_out;

    constexpr size_t PN = (size_t)NPAIR * DP_;      // pnorm floats
    constexpr size_t SN = (size_t)N_ * DP_;         // snorm floats
    float* pnorm = (float*)d_ws;
    constexpr int SNB = (N_ + 255) / 256;

    const size_t need_full = (PN + SN) * sizeof(float) + (size_t)NPAIR * 8 + 64;
    const size_t need_min  = PN * sizeof(float) + (size_t)NPAIR * 8 + 64;

    if (ws_size >= need_full) {
        float* snorm = pnorm + PN;
        unsigned long long* res =
            (unsigned long long*)(((uintptr_t)(snorm + SN) + 7) & ~(uintptr_t)7);
        hipMemsetAsync(res, 0, (size_t)NPAIR * 8, stream);
        prep_kernel<<<B_ + SNB, 256, 0, stream>>>(x, W1, b1, W2, b2, W3, b3, songs,
                                                  pnorm, snorm, 1);
        sim10_kernel<<<NBLK, TPB10, 0, stream>>>(pnorm, snorm, res);
        gather_kernel<<<(NPAIR + 255) / 256, 256, 0, stream>>>(res, songs, out);
    } else if (ws_size >= need_min) {
        unsigned long long* res =
            (unsigned long long*)(((uintptr_t)(pnorm + PN) + 7) & ~(uintptr_t)7);
        hipMemsetAsync(res, 0, (size_t)NPAIR * 8, stream);
        prep_kernel<<<B_, 256, 0, stream>>>(x, W1, b1, W2, b2, W3, b3, songs,
                                            pnorm, nullptr, 0);
        constexpr int FNCH = 250;
        sim6f_kernel<FNCH><<<dim3(FNCH, NPAIR / 256), 256, 0, stream>>>(pnorm, songs, res);
        gather_kernel<<<(NPAIR + 255) / 256, 256, 0, stream>>>(res, songs, out);
    }
}